// Round 13
// baseline (63.388 us; speedup 1.0000x reference)
//
#include <hip/hip_runtime.h>

#define NB 4
#define NV 256
#define NF 256
#define IMG 128
#define FSTR 32   // floats per FACE record (30 used + 2 pad, 128B)

#define CONST_AS __attribute__((address_space(4)))

__device__ __forceinline__ float rcpf(float x) { return __builtin_amdgcn_rcpf(x); }
__device__ __forceinline__ float ex2(float x)  { return __builtin_amdgcn_exp2f(x); }
__device__ __forceinline__ float med01(float x) { return __builtin_amdgcn_fmed3f(x, 0.0f, 1.0f); }

#define SCV   120.11224139682566f    // sqrt((1/SIGMA)*log2(e))
#define KGAMV 14.426950408889634f    // (1/GAMMA)*log2(e)

// face record (face f of batch b at ws + (b*256+f)*FSTR), geometry scaled by SC:
//  0 a0x_s  1 a0y_s  2 a1x_s  3 a1y_s  4 a2x_s  5 a2y_s
//  6 e01x_s 7 e01y_s 8 e12x_s 9 e12y_s 10 e20x_s 11 e20y_s
// 12 g01x' 13 g01y' 14 g12x' 15 g12y' 16 g20x' 17 g20y'    (g' = e*ib/SC)
// 18 h12x 19 h12y 20 h20x 21 h20y                          (h = e*idn/SC)
// 22 z0 23 z1 24 z2 25 cr 26 cg 27 cb

__global__ void prep_faces(const float* __restrict__ verts,
                           const int* __restrict__ faces,
                           const float* __restrict__ colors,
                           const float* __restrict__ eye,
                           float* __restrict__ ws)
{
    const int b = blockIdx.x;      // 0..3
    const int f = threadIdx.x;     // 0..255

    const float fpj = 1.7320508075688772f;
    const float p22 = -1.0202020202020203f;
    const float p23 = -0.20202020202020202f;

    float ex = eye[b*3+0], ey = eye[b*3+1], ez = eye[b*3+2];
    float en  = sqrtf(ex*ex + ey*ey + ez*ez);
    float izn = 1.0f / (en + 1e-8f);
    float zx = ex*izn, zy = ey*izn, zz = ez*izn;
    float cn  = sqrtf(zz*zz + zx*zx);
    float ixn = 1.0f / (cn + 1e-8f);
    float xx = zz*ixn, xy = 0.0f, xz = -zx*ixn;
    float yx = zy*xz - zz*xy;
    float yy = zz*xx - zx*xz;
    float yz = zx*xy - zy*xx;
    float tx = -(xx*ex + xy*ey + xz*ez);
    float ty = -(yx*ex + yy*ey + yz*ez);
    float tz = -(zx*ex + zy*ey + zz*ez);

    int i0 = faces[f*3+0], i1 = faces[f*3+1], i2 = faces[f*3+2];
    int idx[3] = { i0, i1, i2 };

    float ax[3], ay[3], az[3];
#pragma unroll
    for (int k = 0; k < 3; ++k) {
        const float* v = verts + (b*NV + idx[k])*3;
        float vx = v[0], vy = v[1], vz = v[2];
        float cx  = fpj*(xx*vx + xy*vy + xz*vz + tx);
        float cyv = fpj*(yx*vx + yy*vy + yz*vz + ty);
        float zv  = zx*vx + zy*vy + zz*vz + tz;
        float cz  = p22*zv + p23;
        float cw  = -zv;
        float iw  = 1.0f / (cw + 1e-8f);
        ax[k] = cx*iw; ay[k] = cyv*iw; az[k] = cz*iw;
    }

    float a0x = ax[0], a0y = ay[0];
    float a1x = ax[1], a1y = ay[1];
    float a2x = ax[2], a2y = ay[2];

    float e01x = a1x - a0x, e01y = a1y - a0y;
    float e12x = a2x - a1x, e12y = a2y - a1y;
    float e20x = a0x - a2x, e20y = a0y - a2y;

    float area  = e01x*(a2y - a0y) - e01y*(a2x - a0x);
    float denom = area + (area >= 0.0f ? 1e-12f : -1e-12f);
    float idn   = 1.0f / denom;

    float ib01 = 1.0f / (e01x*e01x + e01y*e01y + 1e-12f);
    float ib12 = 1.0f / (e12x*e12x + e12y*e12y + 1e-12f);
    float ib20 = 1.0f / (e20x*e20x + e20y*e20y + 1e-12f);

    const float third = (1.0f/3.0f);
    float cr = (colors[(b*NV+i0)*3+0] + colors[(b*NV+i1)*3+0] + colors[(b*NV+i2)*3+0]) * third;
    float cg = (colors[(b*NV+i0)*3+1] + colors[(b*NV+i1)*3+1] + colors[(b*NV+i2)*3+1]) * third;
    float cb = (colors[(b*NV+i0)*3+2] + colors[(b*NV+i1)*3+2] + colors[(b*NV+i2)*3+2]) * third;

    const float ISC = 1.0f / SCV;

    float* o = ws + ((b << 8) + f)*FSTR;
    o[ 0]=a0x*SCV;  o[ 1]=a0y*SCV;
    o[ 2]=a1x*SCV;  o[ 3]=a1y*SCV;
    o[ 4]=a2x*SCV;  o[ 5]=a2y*SCV;
    o[ 6]=e01x*SCV; o[ 7]=e01y*SCV;
    o[ 8]=e12x*SCV; o[ 9]=e12y*SCV;
    o[10]=e20x*SCV; o[11]=e20y*SCV;
    o[12]=e01x*ib01*ISC; o[13]=e01y*ib01*ISC;
    o[14]=e12x*ib12*ISC; o[15]=e12y*ib12*ISC;
    o[16]=e20x*ib20*ISC; o[17]=e20y*ib20*ISC;
    o[18]=e12x*idn*ISC;  o[19]=e12y*idn*ISC;
    o[20]=e20x*idn*ISC;  o[21]=e20y*idn*ISC;
    o[22]=az[0]; o[23]=az[1]; o[24]=az[2];
    o[25]=cr;    o[26]=cg;    o[27]=cb;
    o[28]=0.0f;  o[29]=0.0f;  o[30]=0.0f;  o[31]=0.0f;
}

// grid 1024 = b*256 + pixel-group; block (64,8): lane = pixel, wave cy = 32-face chunk.
// Pure scalar body; all face constants arrive via wave-uniform const-AS (SMEM s_load),
// every VALU op has <=1 SGPR operand (constant-bus clean). No LDS in the loop.
__launch_bounds__(512, 4)
__global__ void raster(const float* __restrict__ ws, float* __restrict__ out)
{
    __shared__ float red[5*8*64];   // 10KB, reduction only

    const int t   = threadIdx.x;   // 0..63
    const int cy  = threadIdx.y;   // 0..7
    const int bid = blockIdx.x;
    const int b   = bid >> 8;
    const int grp = bid & 255;
    const int pix = grp*64 + t;
    const int h = pix >> 7;
    const int w = pix & 127;

    const float pxs = ((w + 0.5f) * (1.0f/64.0f) - 1.0f) * SCV;
    const float pys = (1.0f - (h + 0.5f) * (1.0f/64.0f)) * SCV;

    const CONST_AS float* fc =
        (const CONST_AS float*)(unsigned long long)(ws + (((b << 8) + (cy << 5)) << 5));

    float P = 1.0f, S = 0.0f, R0 = 0.0f, R1 = 0.0f, R2 = 0.0f;

#pragma unroll 4
    for (int i = 0; i < 32; ++i) {
        const CONST_AS float* c = fc + (i << 5);

        // pa vectors (scaled space): 6 subs
        float pa0x = pxs - c[0], pa0y = pys - c[1];
        float pa1x = pxs - c[2], pa1y = pys - c[3];
        float pa2x = pxs - c[4], pa2y = pys - c[5];

        // barycentrics via cross2 (h = e*idn/SC): 2 instr each, b2 affine identity
        float b0 = fmaf(c[18], pa1y, -(c[19]*pa1x));
        float b1 = fmaf(c[20], pa2y, -(c[21]*pa2x));
        float b2 = (1.0f - b0) - b1;

        // 3 point-segment sq-distances (scaled = KSIG*d^2): 7 instr each
        float tt = med01(fmaf(c[12], pa0x, c[13]*pa0y));
        float dx = fmaf(-tt, c[6], pa0x);
        float dy = fmaf(-tt, c[7], pa0y);
        float dd0 = fmaf(dx, dx, dy*dy);

        tt = med01(fmaf(c[14], pa1x, c[15]*pa1y));
        dx = fmaf(-tt, c[8], pa1x);
        dy = fmaf(-tt, c[9], pa1y);
        float dd1 = fmaf(dx, dx, dy*dy);

        tt = med01(fmaf(c[16], pa2x, c[17]*pa2y));
        dx = fmaf(-tt, c[10], pa2x);
        dy = fmaf(-tt, c[11], pa2y);
        float dd2 = fmaf(dx, dx, dy*dy);

        // min3 / max3(neg mods) / bfi
        float dd = fminf(fminf(dd0, dd1), dd2);
        float mx = fmaxf(fmaxf(-b0, -b1), -b2);
        float q  = copysignf(dd, mx);

        // sigmoid
        float prob = rcpf(1.0f + ex2(q));
        P = fmaf(-prob, P, P);

        // clamped barycentrics -> z -> weight (s >= 1/3 always, eps unneeded)
        float bc0 = med01(b0), bc1 = med01(b1), bc2 = med01(b2);
        float s  = (bc0 + bc1) + bc2;
        float zs = fmaf(c[24], bc2, fmaf(c[23], bc1, bc0*c[22]));
        float zq = fmaf(zs * rcpf(s), -0.5f*KGAMV, 0.5f*KGAMV);
        float ez = ex2(__builtin_amdgcn_fmed3f(zq, 0.0f, KGAMV));
        float wgt = prob * ez;

        S += wgt;
        R0 = fmaf(wgt, c[25], R0);
        R1 = fmaf(wgt, c[26], R1);
        R2 = fmaf(wgt, c[27], R2);
    }

    red[(0*8 + cy)*64 + t] = P;
    red[(1*8 + cy)*64 + t] = S;
    red[(2*8 + cy)*64 + t] = R0;
    red[(3*8 + cy)*64 + t] = R1;
    red[(4*8 + cy)*64 + t] = R2;
    __syncthreads();

    if (cy == 0) {
        float Pt = 1.0f, St = 0.0f, r0 = 0.0f, r1 = 0.0f, r2 = 0.0f;
#pragma unroll
        for (int c2 = 0; c2 < 8; ++c2) {
            Pt *= red[(0*8 + c2)*64 + t];
            St += red[(1*8 + c2)*64 + t];
            r0 += red[(2*8 + c2)*64 + t];
            r1 += red[(3*8 + c2)*64 + t];
            r2 += red[(4*8 + c2)*64 + t];
        }
        float iden = rcpf(St + 1.0f);   // background weight = exp2(0) = 1

        out[b*16384 + pix] = 1.0f - Pt;
        float* rgb = out + 65536;
        rgb[(b*3 + 0)*16384 + pix] = r0 * iden;
        rgb[(b*3 + 1)*16384 + pix] = r1 * iden;
        rgb[(b*3 + 2)*16384 + pix] = r2 * iden;
    }
}

extern "C" void kernel_launch(void* const* d_in, const int* in_sizes, int n_in,
                              void* d_out, int out_size, void* d_ws, size_t ws_size,
                              hipStream_t stream)
{
    const float* verts  = (const float*)d_in[0];
    const int*   faces  = (const int*)d_in[1];
    const float* colors = (const float*)d_in[2];
    const float* eye    = (const float*)d_in[3];
    float* out = (float*)d_out;
    float* ws  = (float*)d_ws;   // 4*256 faces * 32 floats = 128 KB

    hipLaunchKernelGGL(prep_faces, dim3(4),    dim3(256),   0, stream,
                       verts, faces, colors, eye, ws);
    hipLaunchKernelGGL(raster,     dim3(1024), dim3(64, 8), 0, stream, ws, out);
}

// Round 14
// 36.494 us; speedup vs baseline: 1.7369x; 1.7369x over previous
//
#include <hip/hip_runtime.h>

#define NB 4
#define NV 256
#define NF 256
#define IMG 128
#define FSTR 32   // floats per FACE record (28 used + 4 pad, 128B)

typedef float sf16 __attribute__((ext_vector_type(16)));

__device__ __forceinline__ float rcpf(float x) { return __builtin_amdgcn_rcpf(x); }
__device__ __forceinline__ float ex2(float x)  { return __builtin_amdgcn_exp2f(x); }
__device__ __forceinline__ float med01(float x) { return __builtin_amdgcn_fmed3f(x, 0.0f, 1.0f); }

#define SCV   120.11224139682566f    // sqrt((1/SIGMA)*log2(e))
#define KGAMV 14.426950408889634f    // (1/GAMMA)*log2(e)

// face record (face f of batch b at ws + (b*256+f)*FSTR), geometry scaled by SC:
//  A[0..5]  a0x a0y a1x a1y a2x a2y           (*SC)
//  A[6..11] e01x e01y e12x e12y e20x e20y     (*SC)
//  A[12..15] g01x g01y g12x g12y               (g = e*ib/SC)
//  B[0..1]  g20x g20y
//  B[2..5]  h12x h12y h20x h20y                (h = e*idn/SC)
//  B[6..8]  z0 z1 z2     B[9..11] cr cg cb

__global__ void prep_faces(const float* __restrict__ verts,
                           const int* __restrict__ faces,
                           const float* __restrict__ colors,
                           const float* __restrict__ eye,
                           float* __restrict__ ws)
{
    const int b = blockIdx.x;      // 0..3
    const int f = threadIdx.x;     // 0..255

    const float fpj = 1.7320508075688772f;
    const float p22 = -1.0202020202020203f;
    const float p23 = -0.20202020202020202f;

    float ex = eye[b*3+0], ey = eye[b*3+1], ez = eye[b*3+2];
    float en  = sqrtf(ex*ex + ey*ey + ez*ez);
    float izn = 1.0f / (en + 1e-8f);
    float zx = ex*izn, zy = ey*izn, zz = ez*izn;
    float cn  = sqrtf(zz*zz + zx*zx);
    float ixn = 1.0f / (cn + 1e-8f);
    float xx = zz*ixn, xy = 0.0f, xz = -zx*ixn;
    float yx = zy*xz - zz*xy;
    float yy = zz*xx - zx*xz;
    float yz = zx*xy - zy*xx;
    float tx = -(xx*ex + xy*ey + xz*ez);
    float ty = -(yx*ex + yy*ey + yz*ez);
    float tz = -(zx*ex + zy*ey + zz*ez);

    int i0 = faces[f*3+0], i1 = faces[f*3+1], i2 = faces[f*3+2];
    int idx[3] = { i0, i1, i2 };

    float ax[3], ay[3], az[3];
#pragma unroll
    for (int k = 0; k < 3; ++k) {
        const float* v = verts + (b*NV + idx[k])*3;
        float vx = v[0], vy = v[1], vz = v[2];
        float cx  = fpj*(xx*vx + xy*vy + xz*vz + tx);
        float cyv = fpj*(yx*vx + yy*vy + yz*vz + ty);
        float zv  = zx*vx + zy*vy + zz*vz + tz;
        float cz  = p22*zv + p23;
        float cw  = -zv;
        float iw  = 1.0f / (cw + 1e-8f);
        ax[k] = cx*iw; ay[k] = cyv*iw; az[k] = cz*iw;
    }

    float a0x = ax[0], a0y = ay[0];
    float a1x = ax[1], a1y = ay[1];
    float a2x = ax[2], a2y = ay[2];

    float e01x = a1x - a0x, e01y = a1y - a0y;
    float e12x = a2x - a1x, e12y = a2y - a1y;
    float e20x = a0x - a2x, e20y = a0y - a2y;

    float area  = e01x*(a2y - a0y) - e01y*(a2x - a0x);
    float denom = area + (area >= 0.0f ? 1e-12f : -1e-12f);
    float idn   = 1.0f / denom;

    float ib01 = 1.0f / (e01x*e01x + e01y*e01y + 1e-12f);
    float ib12 = 1.0f / (e12x*e12x + e12y*e12y + 1e-12f);
    float ib20 = 1.0f / (e20x*e20x + e20y*e20y + 1e-12f);

    const float third = (1.0f/3.0f);
    float cr = (colors[(b*NV+i0)*3+0] + colors[(b*NV+i1)*3+0] + colors[(b*NV+i2)*3+0]) * third;
    float cg = (colors[(b*NV+i0)*3+1] + colors[(b*NV+i1)*3+1] + colors[(b*NV+i2)*3+1]) * third;
    float cb = (colors[(b*NV+i0)*3+2] + colors[(b*NV+i1)*3+2] + colors[(b*NV+i2)*3+2]) * third;

    const float ISC = 1.0f / SCV;

    float* o = ws + ((b << 8) + f)*FSTR;
    o[ 0]=a0x*SCV;  o[ 1]=a0y*SCV;
    o[ 2]=a1x*SCV;  o[ 3]=a1y*SCV;
    o[ 4]=a2x*SCV;  o[ 5]=a2y*SCV;
    o[ 6]=e01x*SCV; o[ 7]=e01y*SCV;
    o[ 8]=e12x*SCV; o[ 9]=e12y*SCV;
    o[10]=e20x*SCV; o[11]=e20y*SCV;
    o[12]=e01x*ib01*ISC; o[13]=e01y*ib01*ISC;
    o[14]=e12x*ib12*ISC; o[15]=e12y*ib12*ISC;
    o[16]=e20x*ib20*ISC; o[17]=e20y*ib20*ISC;
    o[18]=e12x*idn*ISC;  o[19]=e12y*idn*ISC;
    o[20]=e20x*idn*ISC;  o[21]=e20y*idn*ISC;
    o[22]=az[0]; o[23]=az[1]; o[24]=az[2];
    o[25]=cr;    o[26]=cg;    o[27]=cb;
    o[28]=0.0f;  o[29]=0.0f;  o[30]=0.0f;  o[31]=0.0f;
}

// grid 1024 = b*256 + pixel-group; block (64,8): lane = pixel, wave cy = 32-face chunk.
// Face constants fetched with explicit s_load_dwordx16 into SGPR tuples: scalar VALU
// body, <=1 SGPR operand per instruction, no LDS / no VMEM / no address VALU in loop.
__launch_bounds__(512, 8)
__global__ void raster(const float* __restrict__ ws, float* __restrict__ out)
{
    __shared__ float red[5*8*64];   // 10KB, reduction only

    const int t   = threadIdx.x;   // 0..63
    const int cy  = threadIdx.y;   // 0..7
    const int bid = blockIdx.x;
    const int b   = bid >> 8;
    const int grp = bid & 255;
    const int pix = grp*64 + t;
    const int h = pix >> 7;
    const int w = pix & 127;

    const float pxs = ((w + 0.5f) * (1.0f/64.0f) - 1.0f) * SCV;
    const float pys = (1.0f - (h + 0.5f) * (1.0f/64.0f)) * SCV;

    // wave-uniform byte offset of this wave's 32-face chunk
    int foff = ((b << 8) + (cy << 5)) << 7;           // faces * 128B
    foff = __builtin_amdgcn_readfirstlane(foff);
    unsigned long long cpa = (unsigned long long)ws + (unsigned long long)(unsigned)foff;

    float P = 1.0f, S = 0.0f, R0 = 0.0f, R1 = 0.0f, R2 = 0.0f;

    for (int i = 0; i < 32; ++i) {
        sf16 A, B;
        asm volatile(
            "s_load_dwordx16 %0, %2, 0x0\n\t"
            "s_load_dwordx16 %1, %2, 0x40\n\t"
            "s_waitcnt lgkmcnt(0)"
            : "=s"(A), "=s"(B)
            : "s"(cpa));

        // pa vectors (scaled space)
        float pa0x = pxs - A[0], pa0y = pys - A[1];
        float pa1x = pxs - A[2], pa1y = pys - A[3];
        float pa2x = pxs - A[4], pa2y = pys - A[5];

        // barycentrics via cross2 with h = e*idn/SC; b2 affine identity
        float b0 = fmaf(B[2], pa1y, -(B[3]*pa1x));
        float b1 = fmaf(B[4], pa2y, -(B[5]*pa2x));
        float b2 = (1.0f - b0) - b1;

        // 3 point-segment sq-distances (result pre-scaled = KSIG*log2e*d^2)
        float tt = med01(fmaf(A[12], pa0x, A[13]*pa0y));
        float dx = fmaf(-tt, A[6], pa0x);
        float dy = fmaf(-tt, A[7], pa0y);
        float dd0 = fmaf(dx, dx, dy*dy);

        tt = med01(fmaf(A[14], pa1x, A[15]*pa1y));
        dx = fmaf(-tt, A[8], pa1x);
        dy = fmaf(-tt, A[9], pa1y);
        float dd1 = fmaf(dx, dx, dy*dy);

        tt = med01(fmaf(B[0], pa2x, B[1]*pa2y));
        dx = fmaf(-tt, A[10], pa2x);
        dy = fmaf(-tt, A[11], pa2y);
        float dd2 = fmaf(dx, dx, dy*dy);

        float dd = fminf(fminf(dd0, dd1), dd2);
        float mx = fmaxf(fmaxf(-b0, -b1), -b2);
        float q  = copysignf(dd, mx);

        // sigmoid
        float prob = rcpf(1.0f + ex2(q));
        P = fmaf(-prob, P, P);

        // clamped barycentrics -> z -> weight (s >= 1/3, eps unneeded)
        float bc0 = med01(b0), bc1 = med01(b1), bc2 = med01(b2);
        float s  = (bc0 + bc1) + bc2;
        float zs = fmaf(B[8], bc2, fmaf(B[7], bc1, bc0*B[6]));
        float zq = fmaf(zs * rcpf(s), -0.5f*KGAMV, 0.5f*KGAMV);
        float ez = ex2(__builtin_amdgcn_fmed3f(zq, 0.0f, KGAMV));
        float wgt = prob * ez;

        S += wgt;
        R0 = fmaf(wgt, B[9],  R0);
        R1 = fmaf(wgt, B[10], R1);
        R2 = fmaf(wgt, B[11], R2);

        cpa += 128;   // SALU pointer bump (uniform)
    }

    red[(0*8 + cy)*64 + t] = P;
    red[(1*8 + cy)*64 + t] = S;
    red[(2*8 + cy)*64 + t] = R0;
    red[(3*8 + cy)*64 + t] = R1;
    red[(4*8 + cy)*64 + t] = R2;
    __syncthreads();

    if (cy == 0) {
        float Pt = 1.0f, St = 0.0f, r0 = 0.0f, r1 = 0.0f, r2 = 0.0f;
#pragma unroll
        for (int c2 = 0; c2 < 8; ++c2) {
            Pt *= red[(0*8 + c2)*64 + t];
            St += red[(1*8 + c2)*64 + t];
            r0 += red[(2*8 + c2)*64 + t];
            r1 += red[(3*8 + c2)*64 + t];
            r2 += red[(4*8 + c2)*64 + t];
        }
        float iden = rcpf(St + 1.0f);   // background weight = exp2(0) = 1

        out[b*16384 + pix] = 1.0f - Pt;
        float* rgb = out + 65536;
        rgb[(b*3 + 0)*16384 + pix] = r0 * iden;
        rgb[(b*3 + 1)*16384 + pix] = r1 * iden;
        rgb[(b*3 + 2)*16384 + pix] = r2 * iden;
    }
}

extern "C" void kernel_launch(void* const* d_in, const int* in_sizes, int n_in,
                              void* d_out, int out_size, void* d_ws, size_t ws_size,
                              hipStream_t stream)
{
    const float* verts  = (const float*)d_in[0];
    const int*   faces  = (const int*)d_in[1];
    const float* colors = (const float*)d_in[2];
    const float* eye    = (const float*)d_in[3];
    float* out = (float*)d_out;
    float* ws  = (float*)d_ws;   // 4*256 faces * 32 floats = 128 KB

    hipLaunchKernelGGL(prep_faces, dim3(4),    dim3(256),   0, stream,
                       verts, faces, colors, eye, ws);
    hipLaunchKernelGGL(raster,     dim3(1024), dim3(64, 8), 0, stream, ws, out);
}

// Round 15
// 33.666 us; speedup vs baseline: 1.8829x; 1.0840x over previous
//
#include <hip/hip_runtime.h>

#define NB 4
#define NV 256
#define NF 256
#define IMG 128
#define STR 64   // floats per face-PAIR record (30 slots x 2 = 60, padded to 64 -> 256B)

typedef float v2f __attribute__((ext_vector_type(2)));
typedef float v4f __attribute__((ext_vector_type(4)));

__device__ __forceinline__ float rcpf(float x) { return __builtin_amdgcn_rcpf(x); }
__device__ __forceinline__ float ex2(float x)  { return __builtin_amdgcn_exp2f(x); }
__device__ __forceinline__ float med01(float x) { return __builtin_amdgcn_fmed3f(x, 0.0f, 1.0f); }
__device__ __forceinline__ v2f lo2(v4f q) { return __builtin_shufflevector(q, q, 0, 1); }
__device__ __forceinline__ v2f hi2(v4f q) { return __builtin_shufflevector(q, q, 2, 3); }

// forced VOP3P packed-f32 (CDNA: only add/mul/fma exist packed)
#define PKADD(d,a,b)    asm("v_pk_add_f32 %0, %1, %2"           : "=v"(d) : "v"(a), "v"(b))
#define PKMUL(d,a,b)    asm("v_pk_mul_f32 %0, %1, %2"           : "=v"(d) : "v"(a), "v"(b))
#define PKFMA(d,a,b,c)  asm("v_pk_fma_f32 %0, %1, %2, %3"       : "=v"(d) : "v"(a), "v"(b), "v"(c))
#define PKFMAC(d,a,b,c) asm("v_pk_fma_f32 %0, %1, %2, %3 clamp" : "=v"(d) : "v"(a), "v"(b), "v"(c))

#define SCV   120.11224139682566f    // sqrt((1/SIGMA)*log2(e))
#define KGAMV 14.426950408889634f    // (1/GAMMA)*log2(e)

// pair-interleaved record, slot k of face f at [2k + (f&1)], geometry scaled by SC,
// all values pre-negated as needed so the kernel uses ONLY pk add/mul/fma:
//  0 -a0x  1 -a0y  2 -a1x  3 -a1y  4 -a2x  5 -a2y          (*SC)
//  6 -e01x 7 -e01y 8 -e12x 9 -e12y 10 -e20x 11 -e20y       (*SC)
// 12 g01x 13 g01y 14 g12x 15 g12y 16 g20x 17 g20y          (e*ib/SC)
// 18 h12x 19 -h12y 20 h20x 21 -h20y 22 h01x 23 -h01y       (e*idn/SC)
// 24 z0 25 z1 26 z2 27 cr 28 cg 29 cb

__global__ void prep_faces(const float* __restrict__ verts,
                           const int* __restrict__ faces,
                           const float* __restrict__ colors,
                           const float* __restrict__ eye,
                           float* __restrict__ ws)
{
    const int b = blockIdx.x;      // 0..3
    const int f = threadIdx.x;     // 0..255

    const float fpj = 1.7320508075688772f;
    const float p22 = -1.0202020202020203f;
    const float p23 = -0.20202020202020202f;

    float ex = eye[b*3+0], ey = eye[b*3+1], ez = eye[b*3+2];
    float en  = sqrtf(ex*ex + ey*ey + ez*ez);
    float izn = 1.0f / (en + 1e-8f);
    float zx = ex*izn, zy = ey*izn, zz = ez*izn;
    float cn  = sqrtf(zz*zz + zx*zx);
    float ixn = 1.0f / (cn + 1e-8f);
    float xx = zz*ixn, xy = 0.0f, xz = -zx*ixn;
    float yx = zy*xz - zz*xy;
    float yy = zz*xx - zx*xz;
    float yz = zx*xy - zy*xx;
    float tx = -(xx*ex + xy*ey + xz*ez);
    float ty = -(yx*ex + yy*ey + yz*ez);
    float tz = -(zx*ex + zy*ey + zz*ez);

    int i0 = faces[f*3+0], i1 = faces[f*3+1], i2 = faces[f*3+2];
    int idx[3] = { i0, i1, i2 };

    float ax[3], ay[3], az[3];
#pragma unroll
    for (int k = 0; k < 3; ++k) {
        const float* v = verts + (b*NV + idx[k])*3;
        float vx = v[0], vy = v[1], vz = v[2];
        float cx  = fpj*(xx*vx + xy*vy + xz*vz + tx);
        float cyv = fpj*(yx*vx + yy*vy + yz*vz + ty);
        float zv  = zx*vx + zy*vy + zz*vz + tz;
        float cz  = p22*zv + p23;
        float cw  = -zv;
        float iw  = 1.0f / (cw + 1e-8f);
        ax[k] = cx*iw; ay[k] = cyv*iw; az[k] = cz*iw;
    }

    float a0x = ax[0], a0y = ay[0];
    float a1x = ax[1], a1y = ay[1];
    float a2x = ax[2], a2y = ay[2];

    float e01x = a1x - a0x, e01y = a1y - a0y;
    float e12x = a2x - a1x, e12y = a2y - a1y;
    float e20x = a0x - a2x, e20y = a0y - a2y;

    float area  = e01x*(a2y - a0y) - e01y*(a2x - a0x);
    float denom = area + (area >= 0.0f ? 1e-12f : -1e-12f);
    float idn   = 1.0f / denom;

    float ib01 = 1.0f / (e01x*e01x + e01y*e01y + 1e-12f);
    float ib12 = 1.0f / (e12x*e12x + e12y*e12y + 1e-12f);
    float ib20 = 1.0f / (e20x*e20x + e20y*e20y + 1e-12f);

    const float third = (1.0f/3.0f);
    float cr = (colors[(b*NV+i0)*3+0] + colors[(b*NV+i1)*3+0] + colors[(b*NV+i2)*3+0]) * third;
    float cg = (colors[(b*NV+i0)*3+1] + colors[(b*NV+i1)*3+1] + colors[(b*NV+i2)*3+1]) * third;
    float cb = (colors[(b*NV+i0)*3+2] + colors[(b*NV+i1)*3+2] + colors[(b*NV+i2)*3+2]) * third;

    const float ISC = 1.0f / SCV;

    float* o = ws + (b*128 + (f >> 1))*STR + (f & 1);
    o[ 0]=-a0x*SCV;  o[ 2]=-a0y*SCV;
    o[ 4]=-a1x*SCV;  o[ 6]=-a1y*SCV;
    o[ 8]=-a2x*SCV;  o[10]=-a2y*SCV;
    o[12]=-e01x*SCV; o[14]=-e01y*SCV;
    o[16]=-e12x*SCV; o[18]=-e12y*SCV;
    o[20]=-e20x*SCV; o[22]=-e20y*SCV;
    o[24]=e01x*ib01*ISC; o[26]=e01y*ib01*ISC;
    o[28]=e12x*ib12*ISC; o[30]=e12y*ib12*ISC;
    o[32]=e20x*ib20*ISC; o[34]=e20y*ib20*ISC;
    o[36]=e12x*idn*ISC;  o[38]=-e12y*idn*ISC;
    o[40]=e20x*idn*ISC;  o[42]=-e20y*idn*ISC;
    o[44]=e01x*idn*ISC;  o[46]=-e01y*idn*ISC;
    o[48]=az[0]; o[50]=az[1]; o[52]=az[2];
    o[54]=cr;    o[56]=cg;    o[58]=cb;
}

// grid 1024 = b*256 + pixel-group(64); block (64,8): lane = pixel, wave cy = 16-pair chunk
__launch_bounds__(512, 4)
__global__ void raster(const float* __restrict__ ws, float* __restrict__ out)
{
    __shared__ float sFD[8192];   // 32KB table; reductions aliased after loop

    const int t   = threadIdx.x;   // 0..63
    const int cy  = threadIdx.y;   // 0..7
    const int bid = blockIdx.x;
    const int b   = bid >> 8;
    const int grp = bid & 255;
    const int pix = grp*64 + t;
    const int h = pix >> 7;
    const int w = pix & 127;

    // stage per-batch table: 8192 floats = 2048 float4, 4 per thread
    {
        const float4* src = (const float4*)(ws + (b << 13));
        float4* dst = (float4*)sFD;
        int tid = (cy << 6) + t;    // 0..511
#pragma unroll
        for (int k = 0; k < 4; ++k) dst[tid + (k << 9)] = src[tid + (k << 9)];
    }
    __syncthreads();

    const float pxs = ((w + 0.5f) * (1.0f/64.0f) - 1.0f) * SCV;
    const float pys = (1.0f - (h + 0.5f) * (1.0f/64.0f)) * SCV;
    const v2f PX = { pxs, pxs }, PY = { pys, pys };

    const float* fc = sFD + (cy << 4)*STR;   // this wave's 16 pairs

    float Px = 1.0f, Py = 1.0f;
    float Sx = 0.0f, Sy = 0.0f;
    float R0x = 0.0f, R0y = 0.0f, R1x = 0.0f, R1y = 0.0f, R2x = 0.0f, R2y = 0.0f;

#pragma unroll 2
    for (int i = 0; i < 16; ++i) {
        const float* c = fc + i*STR;
        // 15 x ds_read_b128 (wave-uniform broadcast); float4 j -> slots {2j, 2j+1}
        v4f q0  = *(const v4f*)(c +  0);
        v4f q1  = *(const v4f*)(c +  4);
        v4f q2  = *(const v4f*)(c +  8);
        v4f q3  = *(const v4f*)(c + 12);
        v4f q4  = *(const v4f*)(c + 16);
        v4f q5  = *(const v4f*)(c + 20);
        v4f q6  = *(const v4f*)(c + 24);
        v4f q7  = *(const v4f*)(c + 28);
        v4f q8  = *(const v4f*)(c + 32);
        v4f q9  = *(const v4f*)(c + 36);
        v4f q10 = *(const v4f*)(c + 40);
        v4f q11 = *(const v4f*)(c + 44);
        v4f q12 = *(const v4f*)(c + 48);
        v4f q13 = *(const v4f*)(c + 52);
        v4f q14 = *(const v4f*)(c + 56);
        v2f na0x = lo2(q0),  na0y = hi2(q0);
        v2f na1x = lo2(q1),  na1y = hi2(q1);
        v2f na2x = lo2(q2),  na2y = hi2(q2);
        v2f ne01x = lo2(q3), ne01y = hi2(q3);
        v2f ne12x = lo2(q4), ne12y = hi2(q4);
        v2f ne20x = lo2(q5), ne20y = hi2(q5);
        v2f g01x = lo2(q6),  g01y = hi2(q6);
        v2f g12x = lo2(q7),  g12y = hi2(q7);
        v2f g20x = lo2(q8),  g20y = hi2(q8);
        v2f h12x = lo2(q9),  nh12y = hi2(q9);
        v2f h20x = lo2(q10), nh20y = hi2(q10);
        v2f h01x = lo2(q11), nh01y = hi2(q11);
        v2f z0 = lo2(q12), z1 = hi2(q12);
        v2f z2 = lo2(q13), cr = hi2(q13);
        v2f cg = lo2(q14), cb = hi2(q14);

        // pa = p - a (via pre-negated a): 6 pk
        v2f pa0x; PKADD(pa0x, PX, na0x);  v2f pa0y; PKADD(pa0y, PY, na0y);
        v2f pa1x; PKADD(pa1x, PX, na1x);  v2f pa1y; PKADD(pa1y, PY, na1y);
        v2f pa2x; PKADD(pa2x, PX, na2x);  v2f pa2y; PKADD(pa2y, PY, na2y);

        // barycentrics (independent cross forms, as the reference): 9 pk
        v2f t0; PKMUL(t0, nh12y, pa1x);
        v2f b0; PKFMA(b0, h12x, pa1y, t0);
        v2f bc0; PKFMAC(bc0, h12x, pa1y, t0);
        v2f t1; PKMUL(t1, nh20y, pa2x);
        v2f b1; PKFMA(b1, h20x, pa2y, t1);
        v2f bc1; PKFMAC(bc1, h20x, pa2y, t1);
        v2f t2; PKMUL(t2, nh01y, pa0x);
        v2f b2; PKFMA(b2, h01x, pa0y, t2);
        v2f bc2; PKFMAC(bc2, h01x, pa0y, t2);

        // 3 point-segment sq-distances: 6 pk each (tt clamped via VOP3P clamp)
        v2f u0; PKMUL(u0, pa0y, g01y);
        v2f tt0; PKFMAC(tt0, pa0x, g01x, u0);
        v2f dx0; PKFMA(dx0, tt0, ne01x, pa0x);
        v2f dy0; PKFMA(dy0, tt0, ne01y, pa0y);
        v2f dd0; PKMUL(dd0, dy0, dy0); PKFMA(dd0, dx0, dx0, dd0);

        v2f u1; PKMUL(u1, pa1y, g12y);
        v2f tt1; PKFMAC(tt1, pa1x, g12x, u1);
        v2f dx1; PKFMA(dx1, tt1, ne12x, pa1x);
        v2f dy1; PKFMA(dy1, tt1, ne12y, pa1y);
        v2f dd1; PKMUL(dd1, dy1, dy1); PKFMA(dd1, dx1, dx1, dd1);

        v2f u2; PKMUL(u2, pa2y, g20y);
        v2f tt2; PKFMAC(tt2, pa2x, g20x, u2);
        v2f dx2; PKFMA(dx2, tt2, ne20x, pa2x);
        v2f dy2; PKFMA(dy2, tt2, ne20y, pa2y);
        v2f dd2; PKMUL(dd2, dy2, dy2); PKFMA(dd2, dx2, dx2, dd2);

        // s and zs (packed): 5 pk
        v2f s; PKADD(s, bc0, bc1); PKADD(s, s, bc2);
        v2f zs; PKMUL(zs, bc0, z0); PKFMA(zs, bc1, z1, zs); PKFMA(zs, bc2, z2, zs);

        // PH2 per half: scalar (half-extraction is free)
#define HALF(H, Pp, Ss, Rr0, Rr1, Rr2) {                          \
        float dd = fminf(fminf(dd0.H, dd1.H), dd2.H);             \
        float mx = fmaxf(fmaxf(-b0.H, -b1.H), -b2.H);             \
        float qq = copysignf(dd, mx);                             \
        float e  = ex2(qq);                                       \
        float p  = rcpf(1.0f + e);                                \
        Pp = fmaf(-p, Pp, Pp);                                    \
        float irs = rcpf(s.H);                                    \
        float zp  = zs.H * irs;                                   \
        float zq  = fmaf(zp, -0.5f, 0.5f);                        \
        float zc  = med01(zq) * KGAMV;                            \
        float ezv = ex2(zc);                                      \
        float wv  = p * ezv;                                      \
        Ss += wv;                                                 \
        Rr0 = fmaf(wv, cr.H, Rr0);                                \
        Rr1 = fmaf(wv, cg.H, Rr1);                                \
        Rr2 = fmaf(wv, cb.H, Rr2); }

        HALF(x, Px, Sx, R0x, R1x, R2x)
        HALF(y, Py, Sy, R0y, R1y, R2y)
#undef HALF
    }

    // alias reduction arrays into the table LDS
    __syncthreads();
    float* red = sFD;   // [5][8][64] = 10KB
    red[(0*8 + cy)*64 + t] = Px * Py;
    red[(1*8 + cy)*64 + t] = Sx + Sy;
    red[(2*8 + cy)*64 + t] = R0x + R0y;
    red[(3*8 + cy)*64 + t] = R1x + R1y;
    red[(4*8 + cy)*64 + t] = R2x + R2y;
    __syncthreads();

    if (cy == 0) {
        float P = 1.0f, St = 0.0f, r0 = 0.0f, r1 = 0.0f, r2 = 0.0f;
#pragma unroll
        for (int c2 = 0; c2 < 8; ++c2) {
            P  *= red[(0*8 + c2)*64 + t];
            St += red[(1*8 + c2)*64 + t];
            r0 += red[(2*8 + c2)*64 + t];
            r1 += red[(3*8 + c2)*64 + t];
            r2 += red[(4*8 + c2)*64 + t];
        }
        float iden = rcpf(St + 1.0f);   // background weight = exp2(0) = 1

        out[b*16384 + pix] = 1.0f - P;
        float* rgb = out + 65536;
        rgb[(b*3 + 0)*16384 + pix] = r0 * iden;
        rgb[(b*3 + 1)*16384 + pix] = r1 * iden;
        rgb[(b*3 + 2)*16384 + pix] = r2 * iden;
    }
}

extern "C" void kernel_launch(void* const* d_in, const int* in_sizes, int n_in,
                              void* d_out, int out_size, void* d_ws, size_t ws_size,
                              hipStream_t stream)
{
    const float* verts  = (const float*)d_in[0];
    const int*   faces  = (const int*)d_in[1];
    const float* colors = (const float*)d_in[2];
    const float* eye    = (const float*)d_in[3];
    float* out = (float*)d_out;
    float* ws  = (float*)d_ws;   // 4 * 128 pairs * 64 floats = 128 KB

    hipLaunchKernelGGL(prep_faces, dim3(4),    dim3(256),   0, stream,
                       verts, faces, colors, eye, ws);
    hipLaunchKernelGGL(raster,     dim3(1024), dim3(64, 8), 0, stream, ws, out);
}